// Round 2
// baseline (4146.599 us; speedup 1.0000x reference)
//
#include <hip/hip_runtime.h>
#include <hip/hip_bf16.h>

#define RELS 8

// ---------------- per-(dst,rel) edge counts ----------------
__global__ void count_k(const int* __restrict__ dst, const int* __restrict__ et,
                        float* __restrict__ cnt, int E) {
    int e = blockIdx.x * blockDim.x + threadIdx.x;
    if (e < E) atomicAdd(cnt + (long long)dst[e] * RELS + et[e], 1.0f);
}

__global__ void inv_k(const float* __restrict__ cnt, float* __restrict__ inv, int n) {
    int i = blockIdx.x * blockDim.x + threadIdx.x;
    if (i < n) inv[i] = 1.0f / fmaxf(cnt[i], 1.0f);
}

// ---------------- edge scatter for a relation chunk [r0, r0+Rc) ----------------
// agg layout: [N, Rc, D];  agg[dst, et-r0, :] += x[src, :]
template <int D>
__global__ void scatter_k(const float* __restrict__ x,
                          const int* __restrict__ src,
                          const int* __restrict__ dst,
                          const int* __restrict__ et,
                          float* __restrict__ agg,
                          int E, int r0, int Rc) {
    constexpr int LANES = D / 4;            // float4 per lane
    constexpr int SHIFT = (D == 128) ? 5 : 6;
    int gid = blockIdx.x * blockDim.x + threadIdx.x;
    int e = gid >> SHIFT;
    int lane = gid & (LANES - 1);
    if (e >= E) return;
    int r = et[e] - r0;
    if ((unsigned)r >= (unsigned)Rc) return;
    int s = src[e];
    int d = dst[e];
    const float4 v = *(const float4*)(x + (long long)s * D + lane * 4);
    float* o = agg + ((long long)d * Rc + r) * D + lane * 4;
    atomicAdd(o + 0, v.x);
    atomicAdd(o + 1, v.y);
    atomicAdd(o + 2, v.z);
    atomicAdd(o + 3, v.w);
}

// ---------------- root GEMM: out[n,c] = X[n,:] @ root + bias ----------------
template <int Kd>
__global__ __launch_bounds__(256) void root_gemm(const float* __restrict__ X,
                                                 const float* __restrict__ Wr,
                                                 const float* __restrict__ bias,
                                                 float* __restrict__ out,
                                                 int N, int Co) {
    constexpr int BM = 64, BN = 128, BK = 16;
    __shared__ float As[BK][BM];
    __shared__ float Bs[BK][BN];

    const int row0 = blockIdx.x * BM;
    const int col0 = blockIdx.y * BN;
    const int tid = threadIdx.x;
    const int rt = tid >> 4;
    const int ct = tid & 15;
    const int a_m = tid >> 2;
    const int a_k = (tid & 3) << 2;
    const long long a_row = (long long)min(row0 + a_m, N - 1);
    const int b_k = tid >> 4;
    const int b_c = (tid & 15) << 2;

    float acc[4][8] = {};

    for (int kb = 0; kb < Kd; kb += BK) {
        {
            float4 v = *(const float4*)(X + a_row * Kd + kb + a_k);
            As[a_k + 0][a_m] = v.x;
            As[a_k + 1][a_m] = v.y;
            As[a_k + 2][a_m] = v.z;
            As[a_k + 3][a_m] = v.w;
        }
        {
            const float* Bsrc = Wr + (long long)(kb + b_k) * Co + col0;
            *(float4*)&Bs[b_k][b_c]      = *(const float4*)(Bsrc + b_c);
            *(float4*)&Bs[b_k][b_c + 64] = *(const float4*)(Bsrc + b_c + 64);
        }
        __syncthreads();
#pragma unroll
        for (int kk = 0; kk < BK; ++kk) {
            float4 a  = *(float4*)&As[kk][rt * 4];
            float4 b0 = *(float4*)&Bs[kk][ct * 8];
            float4 b1 = *(float4*)&Bs[kk][ct * 8 + 4];
            float av[4] = {a.x, a.y, a.z, a.w};
            float bv[8] = {b0.x, b0.y, b0.z, b0.w, b1.x, b1.y, b1.z, b1.w};
#pragma unroll
            for (int i = 0; i < 4; ++i)
#pragma unroll
                for (int j = 0; j < 8; ++j)
                    acc[i][j] += av[i] * bv[j];
        }
        __syncthreads();
    }

#pragma unroll
    for (int i = 0; i < 4; ++i) {
        const int row = row0 + rt * 4 + i;
        if (row >= N) continue;
        float* o = out + (long long)row * Co + col0 + ct * 8;
#pragma unroll
        for (int j = 0; j < 8; ++j)
            o[j] = acc[i][j] + bias[col0 + ct * 8 + j];
    }
}

// ---------------- chunk GEMM: out[n,c] += (agg[n,:]*inv) @ W[r0*Kd:, :] ----------------
// agg: [N, Rc, Kd]; scale A[n, rc*Kd+i] by inv[n, r0+rc]. Optionally ReLU on final store.
template <int Kd_SHIFT, bool RELU_OUT>
__global__ __launch_bounds__(256) void agg_gemm(const float* __restrict__ agg,
                                                const float* __restrict__ inv,
                                                const float* __restrict__ W,
                                                float* __restrict__ out,
                                                int N, int Co, int r0, int Rc) {
    constexpr int BM = 64, BN = 128, BK = 16;
    __shared__ float As[BK][BM];
    __shared__ float Bs[BK][BN];

    const int Ktot = Rc << Kd_SHIFT;
    const int row0 = blockIdx.x * BM;
    const int col0 = blockIdx.y * BN;
    const int tid = threadIdx.x;
    const int rt = tid >> 4;
    const int ct = tid & 15;
    const int a_m = tid >> 2;
    const int a_k = (tid & 3) << 2;
    const long long a_row = (long long)min(row0 + a_m, N - 1);
    const int b_k = tid >> 4;
    const int b_c = (tid & 15) << 2;

    float acc[4][8] = {};

    for (int kb = 0; kb < Ktot; kb += BK) {
        {
            const int kg = kb + a_k;
            float4 v = *(const float4*)(agg + a_row * Ktot + kg);
            float scale = inv[a_row * RELS + r0 + (kg >> Kd_SHIFT)];
            As[a_k + 0][a_m] = v.x * scale;
            As[a_k + 1][a_m] = v.y * scale;
            As[a_k + 2][a_m] = v.z * scale;
            As[a_k + 3][a_m] = v.w * scale;
        }
        {
            const int kg = kb + b_k;
            const float* Bsrc = W + ((long long)(r0 << Kd_SHIFT) + kg) * Co + col0;
            *(float4*)&Bs[b_k][b_c]      = *(const float4*)(Bsrc + b_c);
            *(float4*)&Bs[b_k][b_c + 64] = *(const float4*)(Bsrc + b_c + 64);
        }
        __syncthreads();
#pragma unroll
        for (int kk = 0; kk < BK; ++kk) {
            float4 a  = *(float4*)&As[kk][rt * 4];
            float4 b0 = *(float4*)&Bs[kk][ct * 8];
            float4 b1 = *(float4*)&Bs[kk][ct * 8 + 4];
            float av[4] = {a.x, a.y, a.z, a.w};
            float bv[8] = {b0.x, b0.y, b0.z, b0.w, b1.x, b1.y, b1.z, b1.w};
#pragma unroll
            for (int i = 0; i < 4; ++i)
#pragma unroll
                for (int j = 0; j < 8; ++j)
                    acc[i][j] += av[i] * bv[j];
        }
        __syncthreads();
    }

#pragma unroll
    for (int i = 0; i < 4; ++i) {
        const int row = row0 + rt * 4 + i;
        if (row >= N) continue;
        float* o = out + (long long)row * Co + col0 + ct * 8;
#pragma unroll
        for (int j = 0; j < 8; ++j) {
            float v = o[j] + acc[i][j];
            if (RELU_OUT) v = fmaxf(v, 0.0f);
            o[j] = v;
        }
    }
}

extern "C" void kernel_launch(void* const* d_in, const int* in_sizes, int n_in,
                              void* d_out, int out_size, void* d_ws, size_t ws_size,
                              hipStream_t stream) {
    const float* x     = (const float*)d_in[0];
    const int*   ei    = (const int*)d_in[1];   // [2, E]
    const int*   et    = (const int*)d_in[2];   // [E]
    const float* W1    = (const float*)d_in[3]; // [8,128,256]
    const float* root1 = (const float*)d_in[4]; // [128,256]
    const float* b1    = (const float*)d_in[5];
    const float* W2    = (const float*)d_in[6]; // [8,256,128]
    const float* root2 = (const float*)d_in[7]; // [256,128]
    const float* b2    = (const float*)d_in[8];

    const int N = in_sizes[0] / 128;
    const int E = in_sizes[2];
    const int* src = ei;
    const int* dst = ei + E;
    const int NR = N * RELS;

    // Adaptive workspace: agg [N*Rc*256] + h1 [N*256] + cnt [N*R] + inv [N*R]
    size_t baseFloats = (size_t)N * 256 + 2 * (size_t)NR;
    int Rc = 0;
    for (int c = RELS; c >= 1; c >>= 1) {
        if ((baseFloats + (size_t)N * c * 256) * sizeof(float) <= ws_size) { Rc = c; break; }
    }
    if (!Rc) return;  // < ~106 MB workspace: cannot run

    float* agg = (float*)d_ws;
    float* h1  = agg + (size_t)N * Rc * 256;
    float* cnt = h1 + (size_t)N * 256;
    float* inv = cnt + (size_t)NR;

    // counts (shared by both layers)
    hipMemsetAsync(cnt, 0, (size_t)NR * sizeof(float), stream);
    count_k<<<(E + 255) / 256, 256, 0, stream>>>(dst, et, cnt, E);
    inv_k<<<(NR + 255) / 256, 256, 0, stream>>>(cnt, inv, NR);

    // ---------- layer 1: h1 = relu( sum_r mean_r(x) @ W1_r + x @ root1 + b1 ) ----------
    root_gemm<128><<<dim3((N + 63) / 64, 2), 256, 0, stream>>>(x, root1, b1, h1, N, 256);
    for (int r0 = 0; r0 < RELS; r0 += Rc) {
        hipMemsetAsync(agg, 0, (size_t)N * Rc * 128 * sizeof(float), stream);
        long long threads = (long long)E * 32;
        scatter_k<128><<<(int)((threads + 255) / 256), 256, 0, stream>>>(
            x, src, dst, et, agg, E, r0, Rc);
        if (r0 + Rc >= RELS)
            agg_gemm<7, true><<<dim3((N + 63) / 64, 2), 256, 0, stream>>>(
                agg, inv, W1, h1, N, 256, r0, Rc);
        else
            agg_gemm<7, false><<<dim3((N + 63) / 64, 2), 256, 0, stream>>>(
                agg, inv, W1, h1, N, 256, r0, Rc);
    }

    // ---------- layer 2: out = sum_r mean_r(h1) @ W2_r + h1 @ root2 + b2 ----------
    root_gemm<256><<<dim3((N + 63) / 64, 1), 256, 0, stream>>>(h1, root2, b2, (float*)d_out, N, 128);
    for (int r0 = 0; r0 < RELS; r0 += Rc) {
        hipMemsetAsync(agg, 0, (size_t)N * Rc * 256 * sizeof(float), stream);
        long long threads = (long long)E * 64;
        scatter_k<256><<<(int)((threads + 255) / 256), 256, 0, stream>>>(
            h1, src, dst, et, agg, E, r0, Rc);
        agg_gemm<8, false><<<dim3((N + 63) / 64, 1), 256, 0, stream>>>(
            agg, inv, W2, (float*)d_out, N, 128, r0, Rc);
    }
}

// Round 3
// 1335.840 us; speedup vs baseline: 3.1041x; 3.1041x over previous
//
#include <hip/hip_runtime.h>
#include <hip/hip_bf16.h>

#define RELS 8

// ================= CSR build =================
__global__ void count_k(const int* __restrict__ dst, const int* __restrict__ et,
                        int* __restrict__ cnt, int E) {
    int e = blockIdx.x * blockDim.x + threadIdx.x;
    if (e < E) atomicAdd(&cnt[dst[e] * RELS + et[e]], 1);
}

// block scans 2048 elems; writes per-elem exclusive scan + block total
__global__ __launch_bounds__(256) void scan1_k(const int* __restrict__ in,
                                               int* __restrict__ outp,
                                               int* __restrict__ bsum, int n) {
    __shared__ int sh[256];
    const int t = threadIdx.x;
    const int base = blockIdx.x * 2048 + t * 8;
    int v[8]; int s = 0;
#pragma unroll
    for (int j = 0; j < 8; ++j) { int idx = base + j; v[j] = (idx < n) ? in[idx] : 0; s += v[j]; }
    sh[t] = s; __syncthreads();
    for (int off = 1; off < 256; off <<= 1) {
        int x = (t >= off) ? sh[t - off] : 0;
        __syncthreads(); sh[t] += x; __syncthreads();
    }
    if (t == 255) bsum[blockIdx.x] = sh[255];
    int run = t ? sh[t - 1] : 0;
#pragma unroll
    for (int j = 0; j < 8; ++j) { int idx = base + j; if (idx < n) outp[idx] = run; run += v[j]; }
}

// single block: exclusive scan of up to 2048 ints in place
__global__ __launch_bounds__(256) void scan2_k(int* __restrict__ a, int n) {
    __shared__ int sh[256];
    const int t = threadIdx.x;
    const int base = t * 8;
    int v[8]; int s = 0;
#pragma unroll
    for (int j = 0; j < 8; ++j) { int idx = base + j; v[j] = (idx < n) ? a[idx] : 0; s += v[j]; }
    sh[t] = s; __syncthreads();
    for (int off = 1; off < 256; off <<= 1) {
        int x = (t >= off) ? sh[t - off] : 0;
        __syncthreads(); sh[t] += x; __syncthreads();
    }
    int run = t ? sh[t - 1] : 0;
#pragma unroll
    for (int j = 0; j < 8; ++j) { int idx = base + j; if (idx < n) a[idx] = run; run += v[j]; }
}

__global__ void scan3_k(int* __restrict__ outp, const int* __restrict__ bsum, int n) {
    const int base = blockIdx.x * 2048 + threadIdx.x * 8;
    const int add = bsum[blockIdx.x];
#pragma unroll
    for (int j = 0; j < 8; ++j) { int idx = base + j; if (idx < n) outp[idx] += add; }
}

// offs holds exclusive starts; after this kernel offs[seg] == segment end
__global__ void fill_k(const int* __restrict__ dst, const int* __restrict__ et,
                       int* __restrict__ offs, int* __restrict__ order, int E) {
    int e = blockIdx.x * blockDim.x + threadIdx.x;
    if (e < E) {
        int seg = dst[e] * RELS + et[e];
        int p = atomicAdd(&offs[seg], 1);
        order[p] = e;
    }
}

// ================= CSR mean-aggregation: one wave per dst node =================
// agg[node][r][*] = mean over edges in segment (node, r0+r) of X[src]
template <int D, int Rc>
__global__ __launch_bounds__(256) void agg_mean_k(const float* __restrict__ X,
                                                  const int* __restrict__ src,
                                                  const int* __restrict__ order,
                                                  const int* __restrict__ cnt,
                                                  const int* __restrict__ ends,
                                                  float* __restrict__ agg,
                                                  int N, int r0) {
    constexpr int VPL = D / 64;   // floats per lane (2 or 4)
    const int node = blockIdx.x * 4 + (threadIdx.x >> 6);
    const int lane = threadIdx.x & 63;
    if (node >= N) return;
    float acc[Rc][VPL];
#pragma unroll
    for (int r = 0; r < Rc; ++r)
#pragma unroll
        for (int j = 0; j < VPL; ++j) acc[r][j] = 0.0f;

#pragma unroll
    for (int r = 0; r < Rc; ++r) {
        const int seg = node * RELS + r0 + r;
        const int end = ends[seg];
        const int c = cnt[seg];
        for (int idx = end - c; idx < end; ++idx) {
            const int e = order[idx];
            const int s = src[e];
            const float* row = X + (long long)s * D;
            if constexpr (VPL == 2) {
                float2 v = *(const float2*)(row + lane * 2);
                acc[r][0] += v.x; acc[r][1] += v.y;
            } else {
                float4 v = *(const float4*)(row + lane * 4);
                acc[r][0] += v.x; acc[r][1] += v.y; acc[r][2] += v.z; acc[r][3] += v.w;
            }
        }
        const float sc = 1.0f / fmaxf((float)c, 1.0f);
        float* o = agg + ((long long)node * Rc + r) * D;
        if constexpr (VPL == 2) {
            float2 w; w.x = acc[r][0] * sc; w.y = acc[r][1] * sc;
            *(float2*)(o + lane * 2) = w;
        } else {
            float4 w; w.x = acc[r][0] * sc; w.y = acc[r][1] * sc;
            w.z = acc[r][2] * sc; w.w = acc[r][3] * sc;
            *(float4*)(o + lane * 4) = w;
        }
    }
}

// ================= fp32 SIMT GEMM =================
// out[n,c] (+)= [A1 | A2][n,:] @ [B1 ; B2][:,c] (+ bias) (opt ReLU)
// A1: [N, RKd] row-major, A2: [N, Kd], B1: [RKd, Co], B2: [Kd, Co]
template <bool ACCUM, bool RELU>
__global__ __launch_bounds__(256) void gemm_k(const float* __restrict__ A1,
                                              const float* __restrict__ A2,
                                              const float* __restrict__ B1,
                                              const float* __restrict__ B2,
                                              const float* __restrict__ bias,
                                              float* __restrict__ out,
                                              int N, int Co, int RKd, int Kd) {
    constexpr int BM = 64, BN = 128, BK = 16;
    __shared__ float As[BK][BM + 4];   // pad 4: conflict-free transposed writes
    __shared__ float Bs[BK][BN];
    const int Ktot = RKd + Kd;
    const int row0 = blockIdx.x * BM;
    const int col0 = blockIdx.y * BN;
    const int tid = threadIdx.x;
    const int tx = tid & 15;           // 16 col-threads * 8 cols (4 + 4 strided)
    const int ty = tid >> 4;           // 16 row-threads * 4 rows
    const int a_m = tid >> 2;          // 0..63
    const int a_k = (tid & 3) << 2;    // 0,4,8,12
    const int b_k = tid >> 4;          // 0..15
    const int b_c = (tid & 15) << 2;   // 0..60
    const long long arow = (long long)min(row0 + a_m, N - 1);

    float4 pa, pb0, pb1;
    {
        const int kg = a_k;
        pa = (kg < RKd) ? *(const float4*)(A1 + arow * RKd + kg)
                        : *(const float4*)(A2 + arow * Kd + (kg - RKd));
        const int kh = b_k;
        const float* Brow = (kh < RKd) ? (B1 + (long long)kh * Co)
                                       : (B2 + (long long)(kh - RKd) * Co);
        pb0 = *(const float4*)(Brow + col0 + b_c);
        pb1 = *(const float4*)(Brow + col0 + b_c + 64);
    }

    float acc[4][8] = {};

    for (int kb = 0; kb < Ktot; kb += BK) {
        __syncthreads();
        As[a_k + 0][a_m] = pa.x;
        As[a_k + 1][a_m] = pa.y;
        As[a_k + 2][a_m] = pa.z;
        As[a_k + 3][a_m] = pa.w;
        *(float4*)&Bs[b_k][b_c] = pb0;
        *(float4*)&Bs[b_k][b_c + 64] = pb1;
        __syncthreads();
        if (kb + BK < Ktot) {
            const int kg = kb + BK + a_k;
            pa = (kg < RKd) ? *(const float4*)(A1 + arow * RKd + kg)
                            : *(const float4*)(A2 + arow * Kd + (kg - RKd));
            const int kh = kb + BK + b_k;
            const float* Brow = (kh < RKd) ? (B1 + (long long)kh * Co)
                                           : (B2 + (long long)(kh - RKd) * Co);
            pb0 = *(const float4*)(Brow + col0 + b_c);
            pb1 = *(const float4*)(Brow + col0 + b_c + 64);
        }
#pragma unroll
        for (int kk = 0; kk < BK; ++kk) {
            float4 a  = *(float4*)&As[kk][ty * 4];
            float4 b0 = *(float4*)&Bs[kk][tx * 4];
            float4 b1 = *(float4*)&Bs[kk][tx * 4 + 64];
            float av[4] = {a.x, a.y, a.z, a.w};
            float bv[8] = {b0.x, b0.y, b0.z, b0.w, b1.x, b1.y, b1.z, b1.w};
#pragma unroll
            for (int i = 0; i < 4; ++i)
#pragma unroll
                for (int j = 0; j < 8; ++j)
                    acc[i][j] += av[i] * bv[j];
        }
    }

#pragma unroll
    for (int i = 0; i < 4; ++i) {
        const int row = row0 + ty * 4 + i;
        if (row >= N) continue;
        float* o = out + (long long)row * Co + col0;
#pragma unroll
        for (int h = 0; h < 2; ++h) {
            const int cbase = h * 64 + tx * 4;
            float4 v;
            float vv[4];
#pragma unroll
            for (int j = 0; j < 4; ++j) {
                float t = acc[i][h * 4 + j];
                if (ACCUM) t += o[cbase + j];
                else       t += bias[col0 + cbase + j];
                if (RELU) t = fmaxf(t, 0.0f);
                vv[j] = t;
            }
            v.x = vv[0]; v.y = vv[1]; v.z = vv[2]; v.w = vv[3];
            *(float4*)(o + cbase) = v;
        }
    }
}

// ================= launcher =================
extern "C" void kernel_launch(void* const* d_in, const int* in_sizes, int n_in,
                              void* d_out, int out_size, void* d_ws, size_t ws_size,
                              hipStream_t stream) {
    const float* x     = (const float*)d_in[0];
    const int*   ei    = (const int*)d_in[1];
    const int*   et    = (const int*)d_in[2];
    const float* W1    = (const float*)d_in[3];
    const float* root1 = (const float*)d_in[4];
    const float* b1    = (const float*)d_in[5];
    const float* W2    = (const float*)d_in[6];
    const float* root2 = (const float*)d_in[7];
    const float* b2    = (const float*)d_in[8];

    const int N = in_sizes[0] / 128;
    const int E = in_sizes[2];
    const int* src = ei;
    const int* dst = ei + E;
    const int NR = N * RELS;

    // workspace: agg[N*Rc*256] f | h1[N*256] f | cnt[NR] i | offs[NR] i | order[E] i | bsum[4096] i
    const size_t metaElems = (size_t)2 * NR + E + 4096;
    int Rc = 0;
    for (int c = RELS; c >= 1; c >>= 1) {
        size_t need = ((size_t)N * c * 256 + (size_t)N * 256 + metaElems) * 4;
        if (need <= ws_size) { Rc = c; break; }
    }
    if (!Rc) return;

    float* agg  = (float*)d_ws;
    float* h1   = agg + (size_t)N * Rc * 256;
    int*   cnt  = (int*)(h1 + (size_t)N * 256);
    int*   offs = cnt + NR;
    int*   order = offs + NR;
    int*   bsum = order + E;

    // ---- CSR build (once; shared by both layers) ----
    hipMemsetAsync(cnt, 0, (size_t)NR * sizeof(int), stream);
    count_k<<<(E + 255) / 256, 256, 0, stream>>>(dst, et, cnt, E);
    const int nb1 = (NR + 2047) / 2048;
    scan1_k<<<nb1, 256, 0, stream>>>(cnt, offs, bsum, NR);
    scan2_k<<<1, 256, 0, stream>>>(bsum, nb1);
    scan3_k<<<nb1, 256, 0, stream>>>(offs, bsum, NR);
    fill_k<<<(E + 255) / 256, 256, 0, stream>>>(dst, et, offs, order, E);
    // offs now holds segment ENDS; start = end - cnt

    const int aggGrid = (N + 3) / 4;
    const int mBlocks = (N + 63) / 64;

    if (Rc == RELS) {
        // fused single-GEMM per layer: A = [mean | X], B = [W ; root]
        agg_mean_k<128, 8><<<aggGrid, 256, 0, stream>>>(x, src, order, cnt, offs, agg, N, 0);
        gemm_k<false, true><<<dim3(mBlocks, 2), 256, 0, stream>>>(
            agg, x, W1, root1, b1, h1, N, 256, 1024, 128);
        agg_mean_k<256, 8><<<aggGrid, 256, 0, stream>>>(h1, src, order, cnt, offs, agg, N, 0);
        gemm_k<false, false><<<dim3(mBlocks, 1), 256, 0, stream>>>(
            agg, h1, W2, root2, b2, (float*)d_out, N, 128, 2048, 256);
    } else {
        // chunked fallback: root GEMM first, then accumulate per-chunk
        gemm_k<false, false><<<dim3(mBlocks, 2), 256, 0, stream>>>(
            nullptr, x, nullptr, root1, b1, h1, N, 256, 0, 128);
        for (int r0 = 0; r0 < RELS; r0 += Rc) {
            switch (Rc) {
                case 4: agg_mean_k<128, 4><<<aggGrid, 256, 0, stream>>>(x, src, order, cnt, offs, agg, N, r0); break;
                case 2: agg_mean_k<128, 2><<<aggGrid, 256, 0, stream>>>(x, src, order, cnt, offs, agg, N, r0); break;
                default: agg_mean_k<128, 1><<<aggGrid, 256, 0, stream>>>(x, src, order, cnt, offs, agg, N, r0); break;
            }
            const bool last = (r0 + Rc >= RELS);
            if (last)
                gemm_k<true, true><<<dim3(mBlocks, 2), 256, 0, stream>>>(
                    agg, nullptr, W1 + (size_t)r0 * 128 * 256, nullptr, nullptr, h1, N, 256, Rc * 128, 0);
            else
                gemm_k<true, false><<<dim3(mBlocks, 2), 256, 0, stream>>>(
                    agg, nullptr, W1 + (size_t)r0 * 128 * 256, nullptr, nullptr, h1, N, 256, Rc * 128, 0);
        }
        gemm_k<false, false><<<dim3(mBlocks, 1), 256, 0, stream>>>(
            nullptr, h1, nullptr, root2, b2, (float*)d_out, N, 128, 0, 256);
        for (int r0 = 0; r0 < RELS; r0 += Rc) {
            switch (Rc) {
                case 4: agg_mean_k<256, 4><<<aggGrid, 256, 0, stream>>>(h1, src, order, cnt, offs, agg, N, r0); break;
                case 2: agg_mean_k<256, 2><<<aggGrid, 256, 0, stream>>>(h1, src, order, cnt, offs, agg, N, r0); break;
                default: agg_mean_k<256, 1><<<aggGrid, 256, 0, stream>>>(h1, src, order, cnt, offs, agg, N, r0); break;
            }
            gemm_k<true, false><<<dim3(mBlocks, 1), 256, 0, stream>>>(
                agg, nullptr, W2 + (size_t)r0 * 256 * 128, nullptr, nullptr, (float*)d_out, N, 128, Rc * 256, 0);
        }
    }
}

// Round 4
// 545.841 us; speedup vs baseline: 7.5967x; 2.4473x over previous
//
#include <hip/hip_runtime.h>
#include <hip/hip_bf16.h>

#define RELS 8
typedef unsigned int uint;
typedef unsigned short ushort;
typedef __attribute__((ext_vector_type(8))) short short8;
typedef __attribute__((ext_vector_type(4))) float f32x4;

__device__ __forceinline__ float bf2f(ushort h) { return __uint_as_float(((uint)h) << 16); }
__device__ __forceinline__ ushort f2bf(float f) {
    uint u = __float_as_uint(f);
    u += 0x7fffu + ((u >> 16) & 1u);
    return (ushort)(u >> 16);
}

// ================= CSR build =================
__global__ void count_k(const int* __restrict__ dst, const int* __restrict__ et,
                        int* __restrict__ cnt, int E) {
    int e = blockIdx.x * blockDim.x + threadIdx.x;
    if (e < E) atomicAdd(&cnt[dst[e] * RELS + et[e]], 1);
}

__global__ __launch_bounds__(256) void scan1_k(const int* __restrict__ in,
                                               int* __restrict__ outp,
                                               int* __restrict__ bsum, int n) {
    __shared__ int sh[256];
    const int t = threadIdx.x;
    const int base = blockIdx.x * 2048 + t * 8;
    int v[8]; int s = 0;
#pragma unroll
    for (int j = 0; j < 8; ++j) { int idx = base + j; v[j] = (idx < n) ? in[idx] : 0; s += v[j]; }
    sh[t] = s; __syncthreads();
    for (int off = 1; off < 256; off <<= 1) {
        int x = (t >= off) ? sh[t - off] : 0;
        __syncthreads(); sh[t] += x; __syncthreads();
    }
    if (t == 255) bsum[blockIdx.x] = sh[255];
    int run = t ? sh[t - 1] : 0;
#pragma unroll
    for (int j = 0; j < 8; ++j) { int idx = base + j; if (idx < n) outp[idx] = run; run += v[j]; }
}

__global__ __launch_bounds__(256) void scan2_k(int* __restrict__ a, int n) {
    __shared__ int sh[256];
    const int t = threadIdx.x;
    const int base = t * 8;
    int v[8]; int s = 0;
#pragma unroll
    for (int j = 0; j < 8; ++j) { int idx = base + j; v[j] = (idx < n) ? a[idx] : 0; s += v[j]; }
    sh[t] = s; __syncthreads();
    for (int off = 1; off < 256; off <<= 1) {
        int x = (t >= off) ? sh[t - off] : 0;
        __syncthreads(); sh[t] += x; __syncthreads();
    }
    int run = t ? sh[t - 1] : 0;
#pragma unroll
    for (int j = 0; j < 8; ++j) { int idx = base + j; if (idx < n) a[idx] = run; run += v[j]; }
}

__global__ void scan3_k(int* __restrict__ outp, const int* __restrict__ bsum, int n) {
    const int base = blockIdx.x * 2048 + threadIdx.x * 8;
    const int add = bsum[blockIdx.x];
#pragma unroll
    for (int j = 0; j < 8; ++j) { int idx = base + j; if (idx < n) outp[idx] += add; }
}

__global__ void fill_k(const int* __restrict__ dst, const int* __restrict__ et,
                       int* __restrict__ offs, int* __restrict__ order, int E) {
    int e = blockIdx.x * blockDim.x + threadIdx.x;
    if (e < E) {
        int seg = dst[e] * RELS + et[e];
        int p = atomicAdd(&offs[seg], 1);
        order[p] = e;
    }
}

// ================= dtype prep =================
__global__ void cvt_bf16_k(const float* __restrict__ in, ushort* __restrict__ out, long long n4) {
    long long i = ((long long)blockIdx.x * blockDim.x + threadIdx.x) * 4;
    if (i >= n4) return;
    float4 v = *(const float4*)(in + i);
    ushort4 o; o.x = f2bf(v.x); o.y = f2bf(v.y); o.z = f2bf(v.z); o.w = f2bf(v.w);
    *(ushort4*)(out + i) = o;
}

// Bt[c][k] = (k<RK ? W[k][c] : root[k-RK][c]) as bf16
__global__ void makeBt_k(const float* __restrict__ W, const float* __restrict__ root,
                         ushort* __restrict__ Bt, int Co, int RK, int Kd) {
    const int Kt = RK + Kd;
    long long i = (long long)blockIdx.x * blockDim.x + threadIdx.x;
    if (i >= (long long)Co * Kt) return;
    int c = (int)(i / Kt), k = (int)(i % Kt);
    float v = (k < RK) ? W[(long long)k * Co + c] : root[(long long)(k - RK) * Co + c];
    Bt[i] = f2bf(v);
}

// ================= CSR mean-aggregation (bf16 in/out, fp32 accum) =================
// agg[node][r*D + d] = mean over segment (node,r) of X[src][d]
template <int D>
__global__ __launch_bounds__(256) void agg_mean_k(const ushort* __restrict__ X,
                                                  const int* __restrict__ src,
                                                  const int* __restrict__ order,
                                                  const int* __restrict__ cnt,
                                                  const int* __restrict__ ends,
                                                  ushort* __restrict__ agg,
                                                  int N) {
    constexpr int VPL = D / 64;   // bf16 per lane: 2 or 4
    const int node = blockIdx.x * 4 + (threadIdx.x >> 6);
    const int lane = threadIdx.x & 63;
    if (node >= N) return;
#pragma unroll 1
    for (int r = 0; r < RELS; ++r) {
        const int seg = node * RELS + r;
        const int end = ends[seg];
        const int c = cnt[seg];
        float acc[VPL];
#pragma unroll
        for (int j = 0; j < VPL; ++j) acc[j] = 0.0f;
        for (int idx = end - c; idx < end; ++idx) {
            const ushort* row = X + (long long)src[order[idx]] * D + lane * VPL;
            if constexpr (VPL == 2) {
                uint v = *(const uint*)row;
                acc[0] += bf2f((ushort)(v & 0xffffu));
                acc[1] += bf2f((ushort)(v >> 16));
            } else {
                ushort4 v = *(const ushort4*)row;
                acc[0] += bf2f(v.x); acc[1] += bf2f(v.y);
                acc[2] += bf2f(v.z); acc[3] += bf2f(v.w);
            }
        }
        const float sc = 1.0f / fmaxf((float)c, 1.0f);
        ushort* o = agg + (long long)node * (RELS * D) + r * D + lane * VPL;
        if constexpr (VPL == 2) {
            uint pack = (uint)f2bf(acc[0] * sc) | ((uint)f2bf(acc[1] * sc) << 16);
            *(uint*)o = pack;
        } else {
            ushort4 w;
            w.x = f2bf(acc[0] * sc); w.y = f2bf(acc[1] * sc);
            w.z = f2bf(acc[2] * sc); w.w = f2bf(acc[3] * sc);
            *(ushort4*)o = w;
        }
    }
}

// ================= bf16 MFMA GEMM, m97-style =================
// out[m, c] = [A1 | A2][m, :] @ Bt[c, :] + bias[c]   (opt ReLU; out bf16 or f32)
// A1: [M][RKD] bf16, A2: [M][KD] bf16, Bt: [Co][RKD+KD] bf16 (pre-transposed weights)
// Tile 128x128, BK=64, 4 waves (2x2 of 64x64), global_load_lds w=16,
// LDS XOR-swizzle: 16B-slot ^= (row&7) on BOTH source addr and read addr (rule 21).
template <int RKD, int KD, bool RELU, bool OUTBF>
__global__ __launch_bounds__(256) void mfma_gemm_k(const ushort* __restrict__ A1,
                                                   const ushort* __restrict__ A2,
                                                   const ushort* __restrict__ Bt,
                                                   const float* __restrict__ bias,
                                                   void* __restrict__ outv,
                                                   int M, int Co) {
    constexpr int KT = RKD + KD;
    constexpr int NSTEP = KT / 64;
    __shared__ ushort As[128 * 64];
    __shared__ ushort Bs[128 * 64];
    const int tid = threadIdx.x;
    const int l = tid & 63;
    const int w = tid >> 6;
    const int wr = (w >> 1) * 64;
    const int wc = (w & 1) * 64;
    const int row0 = blockIdx.x * 128;
    const int col0 = blockIdx.y * 128;

    // staging geometry: 16 issues of 1KB per tile; wave w owns issues w*4..w*4+3
    int st_r[4], st_sg[4];
#pragma unroll
    for (int i = 0; i < 4; ++i) {
        int S = (w * 4 + i) * 64 + l;       // linear 16B-slot id
        st_r[i] = S >> 3;                   // tile row 0..127
        st_sg[i] = (S & 7) ^ (st_r[i] & 7); // swizzled global 16B-slot within row
    }

    f32x4 acc[4][4];
#pragma unroll
    for (int i = 0; i < 4; ++i)
#pragma unroll
        for (int j = 0; j < 4; ++j)
            acc[i][j] = (f32x4){0.f, 0.f, 0.f, 0.f};

    for (int ks = 0; ks < NSTEP; ++ks) {
        const int k0 = ks * 64;
        __syncthreads();   // prior compute done before LDS overwrite
        // ---- stage A (8KB) ----
#pragma unroll
        for (int i = 0; i < 4; ++i) {
            const int r = st_r[i];
            const int grow = min(row0 + r, M - 1);
            const ushort* gsrc = (k0 < RKD)
                ? A1 + (long long)grow * RKD + k0 + st_sg[i] * 8
                : A2 + (long long)grow * KD + (k0 - RKD) + st_sg[i] * 8;
            __builtin_amdgcn_global_load_lds(
                (const __attribute__((address_space(1))) uint*)gsrc,
                (__attribute__((address_space(3))) uint*)(As + (w * 4 + i) * 512),
                16, 0, 0);
        }
        // ---- stage B (8KB) ----
#pragma unroll
        for (int i = 0; i < 4; ++i) {
            const int r = st_r[i];
            const ushort* gsrc = Bt + (long long)(col0 + r) * KT + k0 + st_sg[i] * 8;
            __builtin_amdgcn_global_load_lds(
                (const __attribute__((address_space(1))) uint*)gsrc,
                (__attribute__((address_space(3))) uint*)(Bs + (w * 4 + i) * 512),
                16, 0, 0);
        }
        __syncthreads();   // compiler drains vmcnt(0) before barrier -> tile ready
        // ---- compute: 2 k-slices of 32 ----
#pragma unroll
        for (int t = 0; t < 2; ++t) {
            short8 a[4], b[4];
#pragma unroll
            for (int i = 0; i < 4; ++i) {
                int r = wr + i * 16 + (l & 15);
                int s = (t * 4 + (l >> 4)) ^ (r & 7);
                a[i] = *(const short8*)(As + r * 64 + s * 8);
            }
#pragma unroll
            for (int j = 0; j < 4; ++j) {
                int r = wc + j * 16 + (l & 15);
                int s = (t * 4 + (l >> 4)) ^ (r & 7);
                b[j] = *(const short8*)(Bs + r * 64 + s * 8);
            }
#pragma unroll
            for (int i = 0; i < 4; ++i)
#pragma unroll
                for (int j = 0; j < 4; ++j)
                    acc[i][j] = __builtin_amdgcn_mfma_f32_16x16x32_bf16(a[i], b[j], acc[i][j], 0, 0, 0);
        }
    }

    // ---- epilogue: C/D map col=lane&15, row=(lane>>4)*4+q ----
    float bj[4];
#pragma unroll
    for (int j = 0; j < 4; ++j) bj[j] = bias[col0 + wc + j * 16 + (l & 15)];
#pragma unroll
    for (int i = 0; i < 4; ++i) {
#pragma unroll
        for (int q = 0; q < 4; ++q) {
            const int row = row0 + wr + i * 16 + (l >> 4) * 4 + q;
            if (row >= M) continue;
#pragma unroll
            for (int j = 0; j < 4; ++j) {
                const int col = col0 + wc + j * 16 + (l & 15);
                float v = acc[i][j][q] + bj[j];
                if (RELU) v = fmaxf(v, 0.0f);
                if (OUTBF) ((ushort*)outv)[(long long)row * Co + col] = f2bf(v);
                else       ((float*)outv)[(long long)row * Co + col] = v;
            }
        }
    }
}

// ================= launcher =================
extern "C" void kernel_launch(void* const* d_in, const int* in_sizes, int n_in,
                              void* d_out, int out_size, void* d_ws, size_t ws_size,
                              hipStream_t stream) {
    const float* x     = (const float*)d_in[0];
    const int*   ei    = (const int*)d_in[1];
    const int*   et    = (const int*)d_in[2];
    const float* W1    = (const float*)d_in[3];
    const float* root1 = (const float*)d_in[4];
    const float* b1    = (const float*)d_in[5];
    const float* W2    = (const float*)d_in[6];
    const float* root2 = (const float*)d_in[7];
    const float* b2    = (const float*)d_in[8];

    const int N = in_sizes[0] / 128;
    const int E = in_sizes[2];
    const int* src = ei;
    const int* dst = ei + E;
    const int NR = N * RELS;

    // bf16 workspace: agg[N*2048] | h1b[N*256] | xb[N*128] | Bt1[256*1152] | Bt2[128*2304]
    // then ints: cnt[NR] | offs[NR] | order[E] | bsum[4096]
    ushort* agg = (ushort*)d_ws;
    ushort* h1b = agg + (size_t)N * 2048;
    ushort* xb  = h1b + (size_t)N * 256;
    ushort* Bt1 = xb + (size_t)N * 128;
    ushort* Bt2 = Bt1 + (size_t)256 * 1152;
    int* cnt   = (int*)(Bt2 + (size_t)128 * 2304);
    int* offs  = cnt + NR;
    int* order = offs + NR;
    int* bsum  = order + E;
    size_t need = ((size_t)N * 2432 + 589824) * 2 + ((size_t)2 * NR + E + 4096) * 4;
    if (need > ws_size) return;

    // ---- dtype prep ----
    {
        long long n4 = (long long)N * 128;
        cvt_bf16_k<<<(int)((n4 / 4 + 255) / 256), 256, 0, stream>>>(x, xb, n4);
    }
    makeBt_k<<<(256 * 1152 + 255) / 256, 256, 0, stream>>>(W1, root1, Bt1, 256, 1024, 128);
    makeBt_k<<<(128 * 2304 + 255) / 256, 256, 0, stream>>>(W2, root2, Bt2, 128, 2048, 256);

    // ---- CSR build ----
    hipMemsetAsync(cnt, 0, (size_t)NR * sizeof(int), stream);
    count_k<<<(E + 255) / 256, 256, 0, stream>>>(dst, et, cnt, E);
    const int nb1 = (NR + 2047) / 2048;
    scan1_k<<<nb1, 256, 0, stream>>>(cnt, offs, bsum, NR);
    scan2_k<<<1, 256, 0, stream>>>(bsum, nb1);
    scan3_k<<<nb1, 256, 0, stream>>>(offs, bsum, NR);
    fill_k<<<(E + 255) / 256, 256, 0, stream>>>(dst, et, offs, order, E);
    // offs now holds segment ENDS; start = end - cnt

    const int aggGrid = (N + 3) / 4;
    const int mBlocks = (N + 127) / 128;

    // ---- layer 1 ----
    agg_mean_k<128><<<aggGrid, 256, 0, stream>>>(xb, src, order, cnt, offs, agg, N);
    mfma_gemm_k<1024, 128, true, true><<<dim3(mBlocks, 2), 256, 0, stream>>>(
        agg, xb, Bt1, b1, h1b, N, 256);

    // ---- layer 2 ----
    agg_mean_k<256><<<aggGrid, 256, 0, stream>>>(h1b, src, order, cnt, offs, agg, N);
    mfma_gemm_k<2048, 256, false, false><<<dim3(mBlocks, 1), 256, 0, stream>>>(
        agg, h1b, Bt2, b2, d_out, N, 128);
}